// Round 10
// baseline (46.713 us; speedup 1.0000x reference)
//
#include <hip/hip_runtime.h>
#include <hip/hip_bf16.h>
#include <math.h>

#define N_NODES 512
#define S_STEPS 64
#define M_EV    32768
#define DELTA_F 1.5625f
#define EPS_F   1e-12f
#define TILE    16
#define NT      (N_NODES / TILE)        // 32
#define NOFF    (NT * (NT - 1) / 2)     // 496 strict-upper tiles
#define NBLK    (NOFF + NT / 2)         // 512 blocks total
#define SCHUNK  16

// ws layout:
//   byte 0:    float4 sC[64]  (c0, 2*c1, c2, T_eff)        1 KB
//   byte 2048: double partials[NBLK*2]                     8 KB

__device__ __forceinline__ int bucket_key(float t) {
    float stepf = floorf(t / DELTA_F);
    float cl = fminf(fmaxf(stepf, 0.f), 63.f);
    return (int)cl;
}

__device__ __forceinline__ int lower_bound_key(const float* __restrict__ data, int target) {
    int lo = 0, len = M_EV;
    while (len > 0) {
        int half = len >> 1;
        int mid = lo + half;
        if (bucket_key(data[3 * mid + 2]) < target) { lo = mid + 1; len -= half + 1; }
        else { len = half; }
    }
    return lo;
}

// branchless erf, Abramowitz-Stegun 7.1.26 (|abs err| ~ 3e-7)
__device__ __forceinline__ float erf_fast(float x) {
    float ax = fabsf(x);
    float t  = __builtin_amdgcn_rcpf(fmaf(0.3275911f, ax, 1.0f));
    float y  = t * fmaf(t, fmaf(t, fmaf(t, fmaf(t, 1.061405429f, -1.453152027f),
                                          1.421413741f), -0.284496736f), 0.254829592f);
    float e  = __expf(-ax * ax);
    float r  = fmaf(-y, e, 1.0f);
    return __builtin_copysignf(r, x);
}

__global__ __launch_bounds__(256) void bucket_stats(const float* __restrict__ data,
                                                    float4* __restrict__ ws_c4) {
    int s   = blockIdx.x;
    int tid = threadIdx.x;
    __shared__ int sLo, sHi;
    __shared__ int   wcnt[4];
    __shared__ float wsdd[4], wsdd2[4];

    if (tid == 0)  sLo = lower_bound_key(data, s);
    if (tid == 64) sHi = lower_bound_key(data, s + 1);
    __syncthreads();
    int lo = sLo, hi = sHi;

    int   cnt = 0;
    float sdd = 0.f, sdd2 = 0.f;
    for (int m = lo + tid; m < hi; m += 256) {
        float t = data[3 * m + 2];
        float stepf = floorf(t / DELTA_F);
        float dd = t - stepf * DELTA_F;
        cnt++; sdd += dd; sdd2 += dd * dd;
    }
    for (int off = 32; off; off >>= 1) {
        cnt  += __shfl_down(cnt,  off);
        sdd  += __shfl_down(sdd,  off);
        sdd2 += __shfl_down(sdd2, off);
    }
    int wave = tid >> 6;
    if ((tid & 63) == 0) { wcnt[wave] = cnt; wsdd[wave] = sdd; wsdd2[wave] = sdd2; }
    __syncthreads();
    if (tid == 0) {
        int   c  = wcnt[0] + wcnt[1] + wcnt[2] + wcnt[3];
        float s1 = wsdd[0] + wsdd[1] + wsdd[2] + wsdd[3];
        float s2 = wsdd2[0] + wsdd2[1] + wsdd2[2] + wsdd2[3];
        float ts = data[3 * min(lo, M_EV - 1) + 2];
        float tf = data[3 * min(hi, M_EV - 1) + 2];
        float Teff = (c > 0) ? (tf - ts) : 0.f;   // T=0 => erf diff == 0 exactly
        ws_c4[s] = make_float4((float)c, 2.f * s1, s2, Teff);
    }
}

__global__ __launch_bounds__(1024, 8) void pair_kernel(
        const float* __restrict__ z0, const float* __restrict__ v0,
        const float* __restrict__ beta, const float4* __restrict__ ws_c4,
        double* __restrict__ partials) {
    __shared__ float4 Pi[S_STEPS][17];
    __shared__ float4 Pj[S_STEPS][17];
    __shared__ float4 sC[64];
    __shared__ double wD[16], wI[16];

    int l = blockIdx.x;
    bool isDiag = (l >= NOFF);
    int it, jt;
    if (!isDiag) {                 // strict upper-tri tile enumeration
        int it_ = 0, rem = l;
        while (rem >= NT - 1 - it_) { rem -= NT - 1 - it_; ++it_; }
        it = it_; jt = it_ + 1 + rem;
    } else {                       // two diagonal tiles per block
        int k = l - NOFF;
        it = 2 * k; jt = 2 * k + 1;
    }

    int tid  = threadIdx.x;
    int wave = tid >> 6, lane = tid & 63;   // 16 waves of 64

    if (tid < 64) sC[tid] = ws_c4[tid];

    // staging: 16 waves x 2 slab entries; lane == step s; wave-64 prefix scan gives Z
    for (int e = wave * 2; e < wave * 2 + 2; ++e) {
        int loc = e & 15;
        int n = (e < 16 ? it : jt) * TILE + loc;
        float vx = v0[n * 128 + lane];
        float vy = v0[n * 128 + 64 + lane];
        float ix = vx, iy = vy;
        #pragma unroll
        for (int off = 1; off < 64; off <<= 1) {
            float ux = __shfl_up(ix, off);
            float uy = __shfl_up(iy, off);
            if (lane >= off) { ix += ux; iy += uy; }
        }
        float zx = fmaf(DELTA_F, ix - vx, z0[2 * n]);      // exclusive prefix
        float zy = fmaf(DELTA_F, iy - vy, z0[2 * n + 1]);
        float4 val = make_float4(zx, zy, vx, vy);
        if (e < 16) Pi[lane][loc] = val; else Pj[lane][loc] = val;
    }
    __syncthreads();

    // compute: 4 chunks x 256 threads; each active thread = one (i,j) pair, 16 steps
    // wave = 4x16 adjacent pairs at the SAME s -> coherent early-out votes
    int chunk = tid >> 8;
    int r  = tid & 255;
    int li = r >> 4, lj = r & 15;

    const float4* rowA;
    const float4* rowB;
    bool act;
    if (!isDiag) {
        rowA = &Pi[0][li]; rowB = &Pj[0][lj]; act = true;
    } else if (li < lj) {
        rowA = &Pi[0][li]; rowB = &Pi[0][lj]; act = true;
    } else {
        int bb = min(li + 1, 15);
        rowA = &Pj[0][lj]; rowB = &Pj[0][bb]; act = (li < 15);
    }

    float accD = 0.f, accI = 0.f;
    float b   = beta[0];
    float thr = b + 20.f;          // skip iff b - (q - por^2) < -20

    if (act) {
        int s0 = chunk * SCHUNK;
        const float4* pA = rowA + s0 * 17;
        const float4* pB = rowB + s0 * 17;
        for (int ss = 0; ss < SCHUNK; ++ss) {
            float4 a = pA[ss * 17];
            float4 c = pB[ss * 17];
            float4 k = sC[s0 + ss];
            float dx  = a.x - c.x,  dy  = a.y - c.y;
            float dvx = a.z - c.z,  dvy = a.w - c.w;
            float q  = dx * dx + dy * dy;
            float p  = fmaf(dx, dvx, dy * dvy);
            float vv = fmaf(dvx, dvx, dvy * dvy);
            accD += fmaf(k.x, q, fmaf(k.y, p, k.z * vv));   // D-part: always
            float rr = vv + EPS_F;
            // division-free: q - p*p/rr > thr  <=>  q*rr - p*p > thr*rr   (rr > 0)
            bool keep = fmaf(q, rr, -p * p) <= thr * rr;
            if (__any(keep)) {          // whole-wave vote; skip 5 transcendentals
                float inv_r = __builtin_amdgcn_rsqf(rr);
                float rt    = rr * inv_r;
                float por   = p * inv_r;
                float ex    = __expf(fmaf(por, por, b - q));
                float integ = ex * (0.8862269254527580f * inv_r)
                              * (erf_fast(fmaf(rt, k.w, por)) - erf_fast(por));
                accI += integ;          // T_eff==0 -> integ==0
            }
        }
    }

    // deterministic reduce: wave tree -> 16 wave partials -> tid 0 sums -> plain store
    for (int off = 32; off; off >>= 1) {
        accD += __shfl_down(accD, off);
        accI += __shfl_down(accI, off);
    }
    if (lane == 0) { wD[wave] = (double)accD; wI[wave] = (double)accI; }
    __syncthreads();
    if (tid == 0) {
        double D = 0.0, I = 0.0;
        #pragma unroll
        for (int k = 0; k < 16; ++k) { D += wD[k]; I += wI[k]; }
        partials[2 * l]     = D;
        partials[2 * l + 1] = I;
    }
}

__global__ void final_reduce(const float* __restrict__ beta,
                             const double* __restrict__ partials,
                             float* __restrict__ out) {
    __shared__ double sD[256], sI[256];
    int tid = threadIdx.x;
    double dD = 0.0, dI = 0.0;
    for (int l = tid; l < NBLK; l += 256) {
        dD += partials[2 * l];
        dI += partials[2 * l + 1];
    }
    sD[tid] = dD; sI[tid] = dI;
    __syncthreads();
    for (int off = 128; off; off >>= 1) {
        if (tid < off) { sD[tid] += sD[tid + off]; sI[tid] += sI[tid + off]; }
        __syncthreads();
    }
    if (tid == 0) {
        double npairs = (double)N_NODES * (double)(N_NODES - 1) * 0.5;
        double ev = (double)beta[0] * (double)M_EV * npairs - sD[0];
        out[0] = (float)(ev - sI[0]);
    }
}

extern "C" void kernel_launch(void* const* d_in, const int* in_sizes, int n_in,
                              void* d_out, int out_size, void* d_ws, size_t ws_size,
                              hipStream_t stream) {
    const float* data = (const float*)d_in[0];
    const float* z0   = (const float*)d_in[3];
    const float* v0   = (const float*)d_in[4];
    const float* beta = (const float*)d_in[5];

    float4* ws_c4    = (float4*)d_ws;
    double* partials = (double*)((char*)d_ws + 2048);
    float*  out      = (float*)d_out;

    bucket_stats<<<64, 256, 0, stream>>>(data, ws_c4);
    pair_kernel<<<NBLK, 1024, 0, stream>>>(z0, v0, beta, ws_c4, partials);
    final_reduce<<<1, 256, 0, stream>>>(beta, partials, out);
}

// Round 11
// 24.989 us; speedup vs baseline: 1.8693x; 1.8693x over previous
//
#include <hip/hip_runtime.h>
#include <hip/hip_bf16.h>
#include <math.h>

#define N_NODES 512
#define S_STEPS 64
#define M_EV    32768
#define DELTA_F 1.5625f
#define TILE    16
#define NT      (N_NODES / TILE)        // 32
#define NOFF    (NT * (NT - 1) / 2)     // 496 strict-upper tiles
#define NBLK    (NOFF + NT / 2)         // 512 blocks total
#define SCHUNK  16
#define GLW1    0.21132486540518713f    // (1 - 1/sqrt(3))/2
#define GLW2    0.78867513459481287f    // (1 + 1/sqrt(3))/2

// ws layout:
//   byte 0:    float4 ws_c4[128]: [s]    = (c0, 2*c1, c2, T/2)
//                                 [64+s] = (t1, t2, t1^2, t2^2),  t_i = T*GLWi
//   byte 4096: double partials[NBLK*2]

__device__ __forceinline__ int bucket_key(float t) {
    float stepf = floorf(t / DELTA_F);
    float cl = fminf(fmaxf(stepf, 0.f), 63.f);
    return (int)cl;
}

__device__ __forceinline__ int lower_bound_key(const float* __restrict__ data, int target) {
    int lo = 0, len = M_EV;
    while (len > 0) {
        int half = len >> 1;
        int mid = lo + half;
        if (bucket_key(data[3 * mid + 2]) < target) { lo = mid + 1; len -= half + 1; }
        else { len = half; }
    }
    return lo;
}

__global__ __launch_bounds__(256) void bucket_stats(const float* __restrict__ data,
                                                    float4* __restrict__ ws_c4) {
    int s   = blockIdx.x;
    int tid = threadIdx.x;
    __shared__ int sLo, sHi;
    __shared__ int   wcnt[4];
    __shared__ float wsdd[4], wsdd2[4];

    if (tid == 0)  sLo = lower_bound_key(data, s);
    if (tid == 64) sHi = lower_bound_key(data, s + 1);
    __syncthreads();
    int lo = sLo, hi = sHi;

    int   cnt = 0;
    float sdd = 0.f, sdd2 = 0.f;
    for (int m = lo + tid; m < hi; m += 256) {
        float t = data[3 * m + 2];
        float stepf = floorf(t / DELTA_F);
        float dd = t - stepf * DELTA_F;
        cnt++; sdd += dd; sdd2 += dd * dd;
    }
    for (int off = 32; off; off >>= 1) {
        cnt  += __shfl_down(cnt,  off);
        sdd  += __shfl_down(sdd,  off);
        sdd2 += __shfl_down(sdd2, off);
    }
    int wave = tid >> 6;
    if ((tid & 63) == 0) { wcnt[wave] = cnt; wsdd[wave] = sdd; wsdd2[wave] = sdd2; }
    __syncthreads();
    if (tid == 0) {
        int   c  = wcnt[0] + wcnt[1] + wcnt[2] + wcnt[3];
        float s1 = wsdd[0] + wsdd[1] + wsdd[2] + wsdd[3];
        float s2 = wsdd2[0] + wsdd2[1] + wsdd2[2] + wsdd2[3];
        float ts = data[3 * min(lo, M_EV - 1) + 2];
        float tf = data[3 * min(hi, M_EV - 1) + 2];
        float T  = (c > 0) ? (tf - ts) : 0.f;          // T=0 -> integ == 0 exactly
        float t1 = T * GLW1, t2 = T * GLW2;
        ws_c4[s]      = make_float4((float)c, 2.f * s1, s2, 0.5f * T);
        ws_c4[64 + s] = make_float4(t1, t2, t1 * t1, t2 * t2);
    }
}

__global__ __launch_bounds__(1024, 8) void pair_kernel(
        const float* __restrict__ z0, const float* __restrict__ v0,
        const float* __restrict__ beta, const float4* __restrict__ ws_c4,
        double* __restrict__ partials) {
    __shared__ float4 Pi[S_STEPS][17];
    __shared__ float4 Pj[S_STEPS][17];
    __shared__ float4 sC[128];
    __shared__ double wD[16], wI[16];

    int l = blockIdx.x;
    bool isDiag = (l >= NOFF);
    int it, jt;
    if (!isDiag) {                 // strict upper-tri tile enumeration
        int it_ = 0, rem = l;
        while (rem >= NT - 1 - it_) { rem -= NT - 1 - it_; ++it_; }
        it = it_; jt = it_ + 1 + rem;
    } else {                       // two diagonal tiles per block
        int k = l - NOFF;
        it = 2 * k; jt = 2 * k + 1;
    }

    int tid  = threadIdx.x;
    int wave = tid >> 6, lane = tid & 63;   // 16 waves of 64

    if (tid < 128) sC[tid] = ws_c4[tid];

    // staging: 16 waves x 2 slab entries; lane == step s; wave-64 prefix scan gives Z
    for (int e = wave * 2; e < wave * 2 + 2; ++e) {
        int loc = e & 15;
        int n = (e < 16 ? it : jt) * TILE + loc;
        float vx = v0[n * 128 + lane];
        float vy = v0[n * 128 + 64 + lane];
        float ix = vx, iy = vy;
        #pragma unroll
        for (int off = 1; off < 64; off <<= 1) {
            float ux = __shfl_up(ix, off);
            float uy = __shfl_up(iy, off);
            if (lane >= off) { ix += ux; iy += uy; }
        }
        float zx = fmaf(DELTA_F, ix - vx, z0[2 * n]);      // exclusive prefix
        float zy = fmaf(DELTA_F, iy - vy, z0[2 * n + 1]);
        float4 val = make_float4(zx, zy, vx, vy);
        if (e < 16) Pi[lane][loc] = val; else Pj[lane][loc] = val;
    }
    __syncthreads();

    // compute: 4 chunks x 256 threads; each active thread = one (i,j) pair, 16 steps
    int chunk = tid >> 8;
    int r  = tid & 255;
    int li = r >> 4, lj = r & 15;

    const float4* rowA;
    const float4* rowB;
    bool act;
    if (!isDiag) {
        rowA = &Pi[0][li]; rowB = &Pj[0][lj]; act = true;
    } else if (li < lj) {
        rowA = &Pi[0][li]; rowB = &Pi[0][lj]; act = true;
    } else {
        int bb = min(li + 1, 15);
        rowA = &Pj[0][lj]; rowB = &Pj[0][bb]; act = (li < 15);
    }

    float accD = 0.f, accI = 0.f;
    float b = beta[0];

    if (act) {
        int s0 = chunk * SCHUNK;
        const float4* pA = rowA + s0 * 17;
        const float4* pB = rowB + s0 * 17;
        const float4* pK1 = &sC[s0];
        const float4* pK2 = &sC[64 + s0];
        #pragma unroll 4
        for (int ss = 0; ss < SCHUNK; ++ss) {
            float4 a  = pA[ss * 17];
            float4 c  = pB[ss * 17];
            float4 k1 = pK1[ss];
            float4 k2 = pK2[ss];
            float dx  = a.x - c.x,  dy  = a.y - c.y;
            float dvx = a.z - c.z,  dvy = a.w - c.w;
            float q  = dx * dx + dy * dy;
            float p  = fmaf(dx, dvx, dy * dvy);
            float vv = fmaf(dvx, dvx, dvy * dvy);
            accD += fmaf(k1.x, q, fmaf(k1.y, p, k1.z * vv));
            // integ = int_0^T exp(b - q - 2p*tau - vv*tau^2) dtau, 2-pt Gauss-Legendre
            float bq = b - q;
            float p2 = p + p;
            float e1 = fmaf(-k2.x, p2, fmaf(-k2.z, vv, bq));
            float e2 = fmaf(-k2.y, p2, fmaf(-k2.w, vv, bq));
            accI = fmaf(k1.w, __expf(e1) + __expf(e2), accI);   // k1.w = T/2 (0 if empty)
        }
    }

    // deterministic reduce: wave tree -> 16 wave partials -> tid 0 sums -> plain store
    for (int off = 32; off; off >>= 1) {
        accD += __shfl_down(accD, off);
        accI += __shfl_down(accI, off);
    }
    if (lane == 0) { wD[wave] = (double)accD; wI[wave] = (double)accI; }
    __syncthreads();
    if (tid == 0) {
        double D = 0.0, I = 0.0;
        #pragma unroll
        for (int k = 0; k < 16; ++k) { D += wD[k]; I += wI[k]; }
        partials[2 * l]     = D;
        partials[2 * l + 1] = I;
    }
}

__global__ void final_reduce(const float* __restrict__ beta,
                             const double* __restrict__ partials,
                             float* __restrict__ out) {
    __shared__ double sD[256], sI[256];
    int tid = threadIdx.x;
    double dD = 0.0, dI = 0.0;
    for (int l = tid; l < NBLK; l += 256) {
        dD += partials[2 * l];
        dI += partials[2 * l + 1];
    }
    sD[tid] = dD; sI[tid] = dI;
    __syncthreads();
    for (int off = 128; off; off >>= 1) {
        if (tid < off) { sD[tid] += sD[tid + off]; sI[tid] += sI[tid + off]; }
        __syncthreads();
    }
    if (tid == 0) {
        double npairs = (double)N_NODES * (double)(N_NODES - 1) * 0.5;
        double ev = (double)beta[0] * (double)M_EV * npairs - sD[0];
        out[0] = (float)(ev - sI[0]);
    }
}

extern "C" void kernel_launch(void* const* d_in, const int* in_sizes, int n_in,
                              void* d_out, int out_size, void* d_ws, size_t ws_size,
                              hipStream_t stream) {
    const float* data = (const float*)d_in[0];
    const float* z0   = (const float*)d_in[3];
    const float* v0   = (const float*)d_in[4];
    const float* beta = (const float*)d_in[5];

    float4* ws_c4    = (float4*)d_ws;
    double* partials = (double*)((char*)d_ws + 4096);
    float*  out      = (float*)d_out;

    bucket_stats<<<64, 256, 0, stream>>>(data, ws_c4);
    pair_kernel<<<NBLK, 1024, 0, stream>>>(z0, v0, beta, ws_c4, partials);
    final_reduce<<<1, 256, 0, stream>>>(beta, partials, out);
}

// Round 12
// 21.528 us; speedup vs baseline: 2.1698x; 1.1608x over previous
//
#include <hip/hip_runtime.h>
#include <hip/hip_bf16.h>
#include <math.h>

#define N_NODES 512
#define S_STEPS 64
#define M_EV    32768
#define DELTA_F 1.5625f
#define TILE    16
#define NT      (N_NODES / TILE)        // 32
#define NOFF    (NT * (NT - 1) / 2)     // 496 strict-upper tiles
#define NBLK    (NOFF + NT / 2)         // 512 blocks total
#define GLW1    0.21132486540518713f    // (1 - 1/sqrt(3))/2
#define GLW2    0.78867513459481287f    // (1 + 1/sqrt(3))/2

// ws layout:
//   byte 0:    float4 ws_c4[128]: [s]    = (c0, 2*c1, c2, T/2)
//                                 [64+s] = (t1, t2, t1^2, t2^2),  t_i = T*GLWi
//   byte 4096: double partials[NBLK*2]

__device__ __forceinline__ int bucket_key(float t) {
    float stepf = floorf(t / DELTA_F);
    float cl = fminf(fmaxf(stepf, 0.f), 63.f);
    return (int)cl;
}

__device__ __forceinline__ int lower_bound_key(const float* __restrict__ data, int target) {
    int lo = 0, len = M_EV;
    while (len > 0) {
        int half = len >> 1;
        int mid = lo + half;
        if (bucket_key(data[3 * mid + 2]) < target) { lo = mid + 1; len -= half + 1; }
        else { len = half; }
    }
    return lo;
}

__global__ __launch_bounds__(256) void bucket_stats(const float* __restrict__ data,
                                                    float4* __restrict__ ws_c4) {
    int s   = blockIdx.x;
    int tid = threadIdx.x;
    __shared__ int sLo, sHi;
    __shared__ int   wcnt[4];
    __shared__ float wsdd[4], wsdd2[4];

    if (tid == 0)  sLo = lower_bound_key(data, s);
    if (tid == 64) sHi = lower_bound_key(data, s + 1);
    __syncthreads();
    int lo = sLo, hi = sHi;

    int   cnt = 0;
    float sdd = 0.f, sdd2 = 0.f;
    for (int m = lo + tid; m < hi; m += 256) {
        float t = data[3 * m + 2];
        float stepf = floorf(t / DELTA_F);
        float dd = t - stepf * DELTA_F;
        cnt++; sdd += dd; sdd2 += dd * dd;
    }
    for (int off = 32; off; off >>= 1) {
        cnt  += __shfl_down(cnt,  off);
        sdd  += __shfl_down(sdd,  off);
        sdd2 += __shfl_down(sdd2, off);
    }
    int wave = tid >> 6;
    if ((tid & 63) == 0) { wcnt[wave] = cnt; wsdd[wave] = sdd; wsdd2[wave] = sdd2; }
    __syncthreads();
    if (tid == 0) {
        int   c  = wcnt[0] + wcnt[1] + wcnt[2] + wcnt[3];
        float s1 = wsdd[0] + wsdd[1] + wsdd[2] + wsdd[3];
        float s2 = wsdd2[0] + wsdd2[1] + wsdd2[2] + wsdd2[3];
        float ts = data[3 * min(lo, M_EV - 1) + 2];
        float tf = data[3 * min(hi, M_EV - 1) + 2];
        float T  = (c > 0) ? (tf - ts) : 0.f;          // T=0 -> integ == 0 exactly
        float t1 = T * GLW1, t2 = T * GLW2;
        ws_c4[s]      = make_float4((float)c, 2.f * s1, s2, 0.5f * T);
        ws_c4[64 + s] = make_float4(t1, t2, t1 * t1, t2 * t2);
    }
}

// one dual-eval: pairs (a0,c) and (a1,c) share c, k1, k2 (k's in SGPRs)
__device__ __forceinline__ void dual_step(const float4 a0, const float4 a1, const float4 c,
                                          const float4 k1, const float4 k2, float b,
                                          float& accD, float& accI) {
    float dx0  = a0.x - c.x,  dy0  = a0.y - c.y;
    float dvx0 = a0.z - c.z,  dvy0 = a0.w - c.w;
    float dx1  = a1.x - c.x,  dy1  = a1.y - c.y;
    float dvx1 = a1.z - c.z,  dvy1 = a1.w - c.w;
    float q0  = dx0 * dx0 + dy0 * dy0;
    float q1  = dx1 * dx1 + dy1 * dy1;
    float p0  = fmaf(dx0, dvx0, dy0 * dvy0);
    float p1  = fmaf(dx1, dvx1, dy1 * dvy1);
    float vv0 = fmaf(dvx0, dvx0, dvy0 * dvy0);
    float vv1 = fmaf(dvx1, dvx1, dvy1 * dvy1);
    accD += fmaf(k1.x, q0, fmaf(k1.y, p0, k1.z * vv0));
    accD += fmaf(k1.x, q1, fmaf(k1.y, p1, k1.z * vv1));
    // integ = int_0^T exp(b - q - 2p*tau - vv*tau^2) dtau, 2-pt Gauss-Legendre
    float bq0 = b - q0, bq1 = b - q1;
    float p20 = p0 + p0, p21 = p1 + p1;
    float e10 = fmaf(-k2.x, p20, fmaf(-k2.z, vv0, bq0));
    float e20 = fmaf(-k2.y, p20, fmaf(-k2.w, vv0, bq0));
    float e11 = fmaf(-k2.x, p21, fmaf(-k2.z, vv1, bq1));
    float e21 = fmaf(-k2.y, p21, fmaf(-k2.w, vv1, bq1));
    accI = fmaf(k1.w, __expf(e10) + __expf(e20), accI);   // k1.w = T/2 (0 if empty)
    accI = fmaf(k1.w, __expf(e11) + __expf(e21), accI);
}

__global__ __launch_bounds__(1024, 8) void pair_kernel(
        const float* __restrict__ z0, const float* __restrict__ v0,
        const float* __restrict__ beta, const float4* __restrict__ ws_c4,
        double* __restrict__ partials) {
    __shared__ float4 Pi[S_STEPS][17];
    __shared__ float4 Pj[S_STEPS][17];
    __shared__ double wD[16], wI[16];

    int l = blockIdx.x;
    bool isDiag = (l >= NOFF);
    int it, jt;
    if (!isDiag) {                 // strict upper-tri tile enumeration
        int it_ = 0, rem = l;
        while (rem >= NT - 1 - it_) { rem -= NT - 1 - it_; ++it_; }
        it = it_; jt = it_ + 1 + rem;
    } else {                       // two diagonal tiles per block
        int k = l - NOFF;
        it = 2 * k; jt = 2 * k + 1;
    }

    int tid  = threadIdx.x;
    int wave = tid >> 6, lane = tid & 63;   // 16 waves of 64

    // staging: 16 waves x 2 slab entries; lane == step s; wave-64 prefix scan gives Z
    for (int e = wave * 2; e < wave * 2 + 2; ++e) {
        int loc = e & 15;
        int n = (e < 16 ? it : jt) * TILE + loc;
        float vx = v0[n * 128 + lane];
        float vy = v0[n * 128 + 64 + lane];
        float ix = vx, iy = vy;
        #pragma unroll
        for (int off = 1; off < 64; off <<= 1) {
            float ux = __shfl_up(ix, off);
            float uy = __shfl_up(iy, off);
            if (lane >= off) { ix += ux; iy += uy; }
        }
        float zx = fmaf(DELTA_F, ix - vx, z0[2 * n]);      // exclusive prefix
        float zy = fmaf(DELTA_F, iy - vy, z0[2 * n + 1]);
        float4 val = make_float4(zx, zy, vx, vy);
        if (e < 16) Pi[lane][loc] = val; else Pj[lane][loc] = val;
    }
    __syncthreads();

    // compute: 8 chunks x 128 threads; thread = pairs (li0,lj),(li0+8,lj), 8 steps
    int chunk = tid >> 7;          // wave-uniform (wave = 64 consecutive tids)
    int r   = tid & 127;
    int lj  = r & 15;
    int li0 = r >> 4;              // 0..7
    int li1 = li0 + 8;             // 8..15

    float accD = 0.f, accI = 0.f;
    float b  = beta[0];
    int sbase = __builtin_amdgcn_readfirstlane(chunk * 8);   // -> SGPR, scalar k loads

    if (!isDiag) {
        const float4* pA0 = &Pi[sbase][li0];
        const float4* pA1 = &Pi[sbase][li1];
        const float4* pC  = &Pj[sbase][lj];
        #pragma unroll
        for (int ss = 0; ss < 8; ++ss) {
            float4 k1 = ws_c4[sbase + ss];        // s_load_dwordx4 (uniform)
            float4 k2 = ws_c4[64 + sbase + ss];
            dual_step(pA0[ss * 17], pA1[ss * 17], pC[ss * 17], k1, k2, b, accD, accI);
        }
    } else {
        // per-pair decode (verified triangle-in-square bijection)
        const float4 *rA0, *rB0, *rA1, *rB1;
        bool act0, act1;
        if (li0 < lj) { rA0 = &Pi[sbase][li0]; rB0 = &Pi[sbase][lj]; act0 = true; }
        else { int bb = min(li0 + 1, 15); rA0 = &Pj[sbase][lj]; rB0 = &Pj[sbase][bb]; act0 = (li0 < 15); }
        if (li1 < lj) { rA1 = &Pi[sbase][li1]; rB1 = &Pi[sbase][lj]; act1 = true; }
        else { int bb = min(li1 + 1, 15); rA1 = &Pj[sbase][lj]; rB1 = &Pj[sbase][bb]; act1 = (li1 < 15); }
        #pragma unroll
        for (int ss = 0; ss < 8; ++ss) {
            float4 k1 = ws_c4[sbase + ss];
            float4 k2 = ws_c4[64 + sbase + ss];
            if (act0) {
                float4 a = rA0[ss * 17], c = rB0[ss * 17];
                float dx = a.x - c.x, dy = a.y - c.y, dvx = a.z - c.z, dvy = a.w - c.w;
                float q = dx * dx + dy * dy;
                float p = fmaf(dx, dvx, dy * dvy);
                float vv = fmaf(dvx, dvx, dvy * dvy);
                accD += fmaf(k1.x, q, fmaf(k1.y, p, k1.z * vv));
                float bq = b - q, p2 = p + p;
                float e1 = fmaf(-k2.x, p2, fmaf(-k2.z, vv, bq));
                float e2 = fmaf(-k2.y, p2, fmaf(-k2.w, vv, bq));
                accI = fmaf(k1.w, __expf(e1) + __expf(e2), accI);
            }
            if (act1) {
                float4 a = rA1[ss * 17], c = rB1[ss * 17];
                float dx = a.x - c.x, dy = a.y - c.y, dvx = a.z - c.z, dvy = a.w - c.w;
                float q = dx * dx + dy * dy;
                float p = fmaf(dx, dvx, dy * dvy);
                float vv = fmaf(dvx, dvx, dvy * dvy);
                accD += fmaf(k1.x, q, fmaf(k1.y, p, k1.z * vv));
                float bq = b - q, p2 = p + p;
                float e1 = fmaf(-k2.x, p2, fmaf(-k2.z, vv, bq));
                float e2 = fmaf(-k2.y, p2, fmaf(-k2.w, vv, bq));
                accI = fmaf(k1.w, __expf(e1) + __expf(e2), accI);
            }
        }
    }

    // deterministic reduce: wave tree -> 16 wave partials -> tid 0 sums -> plain store
    for (int off = 32; off; off >>= 1) {
        accD += __shfl_down(accD, off);
        accI += __shfl_down(accI, off);
    }
    if (lane == 0) { wD[wave] = (double)accD; wI[wave] = (double)accI; }
    __syncthreads();
    if (tid == 0) {
        double D = 0.0, I = 0.0;
        #pragma unroll
        for (int k = 0; k < 16; ++k) { D += wD[k]; I += wI[k]; }
        partials[2 * l]     = D;
        partials[2 * l + 1] = I;
    }
}

__global__ void final_reduce(const float* __restrict__ beta,
                             const double* __restrict__ partials,
                             float* __restrict__ out) {
    __shared__ double sD[256], sI[256];
    int tid = threadIdx.x;
    double dD = 0.0, dI = 0.0;
    for (int l = tid; l < NBLK; l += 256) {
        dD += partials[2 * l];
        dI += partials[2 * l + 1];
    }
    sD[tid] = dD; sI[tid] = dI;
    __syncthreads();
    for (int off = 128; off; off >>= 1) {
        if (tid < off) { sD[tid] += sD[tid + off]; sI[tid] += sI[tid + off]; }
        __syncthreads();
    }
    if (tid == 0) {
        double npairs = (double)N_NODES * (double)(N_NODES - 1) * 0.5;
        double ev = (double)beta[0] * (double)M_EV * npairs - sD[0];
        out[0] = (float)(ev - sI[0]);
    }
}

extern "C" void kernel_launch(void* const* d_in, const int* in_sizes, int n_in,
                              void* d_out, int out_size, void* d_ws, size_t ws_size,
                              hipStream_t stream) {
    const float* data = (const float*)d_in[0];
    const float* z0   = (const float*)d_in[3];
    const float* v0   = (const float*)d_in[4];
    const float* beta = (const float*)d_in[5];

    float4* ws_c4    = (float4*)d_ws;
    double* partials = (double*)((char*)d_ws + 4096);
    float*  out      = (float*)d_out;

    bucket_stats<<<64, 256, 0, stream>>>(data, ws_c4);
    pair_kernel<<<NBLK, 1024, 0, stream>>>(z0, v0, beta, ws_c4, partials);
    final_reduce<<<1, 256, 0, stream>>>(beta, partials, out);
}

// Round 13
// 20.545 us; speedup vs baseline: 2.2737x; 1.0479x over previous
//
#include <hip/hip_runtime.h>
#include <hip/hip_bf16.h>
#include <math.h>

#define N_NODES 512
#define S_STEPS 64
#define M_EV    32768
#define DELTA_F 1.5625f
#define TILE    16
#define NT      (N_NODES / TILE)        // 32
#define NOFF    (NT * (NT - 1) / 2)     // 496 strict-upper tiles
#define NBLK    (NOFF + NT / 2)         // 512 blocks total
#define GLW1    0.21132486540518713f    // (1 - 1/sqrt(3))/2
#define GLW2    0.78867513459481287f    // (1 + 1/sqrt(3))/2
#define INF_I   0x7fffffff

// ws layout:
//   byte 0:     float4 ws_c4[128]: [s]=(c0, 2*c1, c2, T/2), [64+s]=(t1,t2,t1^2,t2^2)
//   byte 2048:  double partials[NBLK*2]                     8 KB
//   byte 16384: float2 slabZ[512][64]                       256 KB

__device__ __forceinline__ int bucket_key(float t) {
    float stepf = floorf(t / DELTA_F);
    float cl = fminf(fmaxf(stepf, 0.f), 63.f);
    return (int)cl;
}

// fused: z-prefix scan (all 16 waves) + bucket stats via 2-round parallel probe
__global__ __launch_bounds__(1024) void prep(const float* __restrict__ data,
                                             const float* __restrict__ z0,
                                             const float* __restrict__ v0,
                                             float4* __restrict__ ws_c4,
                                             float2* __restrict__ slabZ) {
    int blk = blockIdx.x, tid = threadIdx.x;
    int wave = tid >> 6, lane = tid & 63;

    // ---- Part A (all waves): one (node,dim) Z-scan per wave ----
    {
        int nd = blk * 16 + wave;            // 0..1023
        int n = nd >> 1, d = nd & 1;
        float v = v0[n * 128 + d * 64 + lane];
        float ix = v;
        #pragma unroll
        for (int off = 1; off < 64; off <<= 1) {
            float u = __shfl_up(ix, off);
            if (lane >= off) ix += u;
        }
        float z = fmaf(DELTA_F, ix - v, z0[2 * n + d]);   // exclusive prefix
        ((float*)slabZ)[(n * 64 + lane) * 2 + d] = z;
    }

    // ---- Part B (threads 0..255): bucket search for s = blk ----
    __shared__ int redA[4], redB[4];
    __shared__ int sLo, sHi;
    __shared__ int   wcnt[4];
    __shared__ float wsdd[4], wsdd2[4];
    int s = blk;

    if (tid < 256) {                         // L1: probes at m = tid*128
        int m = tid << 7;
        int key = bucket_key(data[3 * m + 2]);
        int cl = (key >= s)     ? m : INF_I;
        int ch = (key >= s + 1) ? m : INF_I;
        for (int off = 32; off; off >>= 1) {
            cl = min(cl, __shfl_down(cl, off));
            ch = min(ch, __shfl_down(ch, off));
        }
        if (lane == 0) { redA[wave] = cl; redB[wave] = ch; }
    }
    __syncthreads();
    if (tid < 256) {                         // L2: sweep the 128-wide bracket
        int posL = min(min(redA[0], redA[1]), min(redA[2], redA[3]));
        int posH = min(min(redB[0], redB[1]), min(redB[2], redB[3]));
        if (posL == INF_I) posL = M_EV;
        if (posH == INF_I) posH = M_EV;
        int base = (tid < 128) ? posL : posH;
        int tgt  = (tid < 128) ? s : s + 1;
        int m2 = base - 127 + (tid & 127);
        int cand = INF_I;
        if (m2 >= 0 && m2 < M_EV && bucket_key(data[3 * m2 + 2]) >= tgt) cand = m2;
        for (int off = 32; off; off >>= 1) cand = min(cand, __shfl_down(cand, off));
        if (lane == 0) redA[wave] = cand;    // waves 0,1 -> lo; waves 2,3 -> hi
    }
    __syncthreads();
    if (tid == 0) {
        int lo = min(redA[0], redA[1]); if (lo == INF_I) lo = M_EV;
        int hi = min(redA[2], redA[3]); if (hi == INF_I) hi = M_EV;
        sLo = lo; sHi = hi;
    }
    __syncthreads();
    int lo = sLo, hi = sHi;
    if (tid < 256) {                         // stats over [lo, hi)
        int   cnt = 0;
        float sdd = 0.f, sdd2 = 0.f;
        for (int m = lo + tid; m < hi; m += 256) {
            float t = data[3 * m + 2];
            float stepf = floorf(t / DELTA_F);
            float dd = t - stepf * DELTA_F;
            cnt++; sdd += dd; sdd2 += dd * dd;
        }
        for (int off = 32; off; off >>= 1) {
            cnt  += __shfl_down(cnt,  off);
            sdd  += __shfl_down(sdd,  off);
            sdd2 += __shfl_down(sdd2, off);
        }
        if (lane == 0) { wcnt[wave] = cnt; wsdd[wave] = sdd; wsdd2[wave] = sdd2; }
    }
    __syncthreads();
    if (tid == 0) {
        int   c  = wcnt[0] + wcnt[1] + wcnt[2] + wcnt[3];
        float s1 = wsdd[0] + wsdd[1] + wsdd[2] + wsdd[3];
        float s2 = wsdd2[0] + wsdd2[1] + wsdd2[2] + wsdd2[3];
        float ts = data[3 * min(lo, M_EV - 1) + 2];
        float tf = data[3 * min(hi, M_EV - 1) + 2];
        float T  = (c > 0) ? (tf - ts) : 0.f;          // T=0 -> integ == 0 exactly
        float t1 = T * GLW1, t2 = T * GLW2;
        ws_c4[s]      = make_float4((float)c, 2.f * s1, s2, 0.5f * T);
        ws_c4[64 + s] = make_float4(t1, t2, t1 * t1, t2 * t2);
    }
}

__device__ __forceinline__ void one_step(const float4 a, const float4 c,
                                         const float4 k1, const float4 k2, float b,
                                         float& accD, float& accI) {
    float dx  = a.x - c.x,  dy  = a.y - c.y;
    float dvx = a.z - c.z,  dvy = a.w - c.w;
    float q  = dx * dx + dy * dy;
    float p  = fmaf(dx, dvx, dy * dvy);
    float vv = fmaf(dvx, dvx, dvy * dvy);
    accD += fmaf(k1.x, q, fmaf(k1.y, p, k1.z * vv));
    float bq = b - q, p2 = p + p;
    float e1 = fmaf(-k2.x, p2, fmaf(-k2.z, vv, bq));
    float e2 = fmaf(-k2.y, p2, fmaf(-k2.w, vv, bq));
    accI = fmaf(k1.w, __expf(e1) + __expf(e2), accI);   // k1.w = T/2 (0 if empty)
}

__global__ __launch_bounds__(1024, 8) void pair_kernel(
        const float* __restrict__ v0, const float* __restrict__ beta,
        const float4* __restrict__ ws_c4, const float2* __restrict__ slabZ,
        double* __restrict__ partials) {
    __shared__ float4 Pi[S_STEPS][17];
    __shared__ float4 Pj[S_STEPS][17];
    __shared__ double wD[16], wI[16];

    int l = blockIdx.x;
    bool isDiag = (l >= NOFF);
    int it, jt;
    if (!isDiag) {
        int it_ = 0, rem = l;
        while (rem >= NT - 1 - it_) { rem -= NT - 1 - it_; ++it_; }
        it = it_; jt = it_ + 1 + rem;
    } else {
        int k = l - NOFF;
        it = 2 * k; jt = 2 * k + 1;
    }

    int tid  = threadIdx.x;
    int wave = tid >> 6, lane = tid & 63;

    // staging: 2 entries/thread, straight copy from precomputed slab (coalesced)
    #pragma unroll
    for (int p = 0; p < 2; ++p) {
        int e   = tid + p * 1024;
        int s   = e & 63;
        int loc = (e >> 6) & 15;
        int n = (p == 0 ? it : jt) * TILE + loc;
        float2 zz = slabZ[n * 64 + s];
        float  vx = v0[n * 128 + s];
        float  vy = v0[n * 128 + 64 + s];
        float4 val = make_float4(zz.x, zz.y, vx, vy);
        if (p == 0) Pi[s][loc] = val; else Pj[s][loc] = val;
    }
    __syncthreads();

    // compute: 16 wave-chunks x 4 steps; thread = 2x2 pair block (1 b128/eval)
    int sbase = __builtin_amdgcn_readfirstlane((tid >> 6) * 4);
    int r   = tid & 63;
    int li0 = r >> 3, li1 = li0 + 8;
    int lj0 = r & 7,  lj1 = lj0 + 8;

    float accD = 0.f, accI = 0.f;
    float b = beta[0];

    if (!isDiag) {
        const float4* pA0 = &Pi[sbase][li0];
        const float4* pA1 = &Pi[sbase][li1];
        const float4* pC0 = &Pj[sbase][lj0];
        const float4* pC1 = &Pj[sbase][lj1];
        #pragma unroll
        for (int ss = 0; ss < 4; ++ss) {
            float4 k1 = ws_c4[sbase + ss];        // s_load_dwordx4 (wave-uniform)
            float4 k2 = ws_c4[64 + sbase + ss];
            float4 a0 = pA0[ss * 17], a1 = pA1[ss * 17];
            float4 c0 = pC0[ss * 17], c1 = pC1[ss * 17];
            one_step(a0, c0, k1, k2, b, accD, accI);
            one_step(a0, c1, k1, k2, b, accD, accI);
            one_step(a1, c0, k1, k2, b, accD, accI);
            one_step(a1, c1, k1, k2, b, accD, accI);
        }
    } else {
        // 4 combos, each decoded via the verified triangle-in-square bijection
        const float4 *A0, *B0, *A1, *B1, *A2, *B2, *A3, *B3;
        bool g0, g1, g2, g3;
        #define DECODE(X, Y, A, B, G) \
            if ((X) < (Y)) { A = &Pi[sbase][X]; B = &Pi[sbase][Y]; G = true; } \
            else { int bb_ = min((X) + 1, 15); A = &Pj[sbase][Y]; B = &Pj[sbase][bb_]; G = ((X) < 15); }
        DECODE(li0, lj0, A0, B0, g0)
        DECODE(li0, lj1, A1, B1, g1)
        DECODE(li1, lj0, A2, B2, g2)
        DECODE(li1, lj1, A3, B3, g3)
        #undef DECODE
        #pragma unroll
        for (int ss = 0; ss < 4; ++ss) {
            float4 k1 = ws_c4[sbase + ss];
            float4 k2 = ws_c4[64 + sbase + ss];
            if (g0) one_step(A0[ss * 17], B0[ss * 17], k1, k2, b, accD, accI);
            if (g1) one_step(A1[ss * 17], B1[ss * 17], k1, k2, b, accD, accI);
            if (g2) one_step(A2[ss * 17], B2[ss * 17], k1, k2, b, accD, accI);
            if (g3) one_step(A3[ss * 17], B3[ss * 17], k1, k2, b, accD, accI);
        }
    }

    // deterministic reduce: wave tree -> 16 wave partials -> tid 0 sums -> store
    for (int off = 32; off; off >>= 1) {
        accD += __shfl_down(accD, off);
        accI += __shfl_down(accI, off);
    }
    if (lane == 0) { wD[wave] = (double)accD; wI[wave] = (double)accI; }
    __syncthreads();
    if (tid == 0) {
        double D = 0.0, I = 0.0;
        #pragma unroll
        for (int k = 0; k < 16; ++k) { D += wD[k]; I += wI[k]; }
        partials[2 * l]     = D;
        partials[2 * l + 1] = I;
    }
}

__global__ void final_reduce(const float* __restrict__ beta,
                             const double* __restrict__ partials,
                             float* __restrict__ out) {
    __shared__ double sD[256], sI[256];
    int tid = threadIdx.x;
    double dD = 0.0, dI = 0.0;
    for (int l = tid; l < NBLK; l += 256) {
        dD += partials[2 * l];
        dI += partials[2 * l + 1];
    }
    sD[tid] = dD; sI[tid] = dI;
    __syncthreads();
    for (int off = 128; off; off >>= 1) {
        if (tid < off) { sD[tid] += sD[tid + off]; sI[tid] += sI[tid + off]; }
        __syncthreads();
    }
    if (tid == 0) {
        double npairs = (double)N_NODES * (double)(N_NODES - 1) * 0.5;
        double ev = (double)beta[0] * (double)M_EV * npairs - sD[0];
        out[0] = (float)(ev - sI[0]);
    }
}

extern "C" void kernel_launch(void* const* d_in, const int* in_sizes, int n_in,
                              void* d_out, int out_size, void* d_ws, size_t ws_size,
                              hipStream_t stream) {
    const float* data = (const float*)d_in[0];
    const float* z0   = (const float*)d_in[3];
    const float* v0   = (const float*)d_in[4];
    const float* beta = (const float*)d_in[5];

    float4* ws_c4    = (float4*)d_ws;
    double* partials = (double*)((char*)d_ws + 2048);
    float2* slabZ    = (float2*)((char*)d_ws + 16384);
    float*  out      = (float*)d_out;

    prep<<<64, 1024, 0, stream>>>(data, z0, v0, ws_c4, slabZ);
    pair_kernel<<<NBLK, 1024, 0, stream>>>(v0, beta, ws_c4, slabZ, partials);
    final_reduce<<<1, 256, 0, stream>>>(beta, partials, out);
}